// Round 1
// baseline (1361.092 us; speedup 1.0000x reference)
//
#include <hip/hip_runtime.h>
#include <hip/hip_bf16.h>

#define D_MODEL 1024
#define D_INNER 2048
#define D_STATE 16
#define D_CONV 4
#define DT_RANK 64
#define NB 2
#define LSEQ 1024
#define NROWS (NB * LSEQ)          // 2048 rows for all row-major GEMMs
#define XPN (DT_RANK + 2 * D_STATE) // 96

// ---------------- LayerNorm: one block per row (1024 cols) ----------------
__global__ __launch_bounds__(256) void ln_kernel(const float* __restrict__ x,
                                                 const float* __restrict__ w,
                                                 const float* __restrict__ bnorm,
                                                 float* __restrict__ out) {
    int row = blockIdx.x;
    const float4* xr = (const float4*)(x + (size_t)row * D_MODEL);
    float4 v = xr[threadIdx.x];
    float s = v.x + v.y + v.z + v.w;
    float sq = v.x * v.x + v.y * v.y + v.z * v.z + v.w * v.w;
#pragma unroll
    for (int off = 32; off > 0; off >>= 1) {
        s += __shfl_down(s, off);
        sq += __shfl_down(sq, off);
    }
    __shared__ float ws[4], wq[4];
    __shared__ float smu, srstd;
    int wave = threadIdx.x >> 6;
    if ((threadIdx.x & 63) == 0) { ws[wave] = s; wq[wave] = sq; }
    __syncthreads();
    if (threadIdx.x == 0) {
        float ts = ws[0] + ws[1] + ws[2] + ws[3];
        float tq = wq[0] + wq[1] + wq[2] + wq[3];
        float mu = ts * (1.f / D_MODEL);
        float var = tq * (1.f / D_MODEL) - mu * mu;
        smu = mu;
        srstd = rsqrtf(var + 1e-5f);
    }
    __syncthreads();
    float mu = smu, rstd = srstd;
    float4 wv = ((const float4*)w)[threadIdx.x];
    float4 bv = ((const float4*)bnorm)[threadIdx.x];
    float4 o;
    o.x = (v.x - mu) * rstd * wv.x + bv.x;
    o.y = (v.y - mu) * rstd * wv.y + bv.y;
    o.z = (v.z - mu) * rstd * wv.z + bv.z;
    o.w = (v.w - mu) * rstd * wv.w + bv.w;
    ((float4*)(out + (size_t)row * D_MODEL))[threadIdx.x] = o;
}

// ---------------- Generic fp32 tiled GEMM: C = A @ B (+ epilogue) ----------------
// A: M x K row-major (lda), B: K x N row-major (ldb = N), C: M x N (ldc).
// 64x64 tile, BK=16, 256 threads, 4x4 microtile. M, K multiples of 16; N multiple of 4.
// EPI: 0 = none, 1 = softplus(x + bias[col])
template <int EPI>
__global__ __launch_bounds__(256) void gemm_f32(const float* __restrict__ A, int lda,
                                                const float* __restrict__ Bw,
                                                const float* __restrict__ bias,
                                                float* __restrict__ C, int ldc,
                                                int M, int N, int K) {
    __shared__ float As[64][17];   // +1 pad: conflict-free column reads
    __shared__ float Bs[16][64];
    int tid = threadIdx.x;
    int cx = tid & 15, ry = tid >> 4;
    int bm = blockIdx.y * 64, bn = blockIdx.x * 64;
    int arow = tid >> 2, acol = (tid & 3) * 4;
    int brow = tid >> 4, bcol = (tid & 15) * 4;
    float acc[4][4] = {};
    for (int k0 = 0; k0 < K; k0 += 16) {
        float4 av = *(const float4*)(A + (size_t)(bm + arow) * lda + (k0 + acol));
        float4 bv = make_float4(0.f, 0.f, 0.f, 0.f);
        if (bn + bcol < N)
            bv = *(const float4*)(Bw + (size_t)(k0 + brow) * N + (bn + bcol));
        __syncthreads();
        As[arow][acol] = av.x; As[arow][acol + 1] = av.y;
        As[arow][acol + 2] = av.z; As[arow][acol + 3] = av.w;
        *(float4*)&Bs[brow][bcol] = bv;
        __syncthreads();
#pragma unroll
        for (int kk = 0; kk < 16; ++kk) {
            float a[4], b[4];
#pragma unroll
            for (int i = 0; i < 4; ++i) a[i] = As[ry * 4 + i][kk];
#pragma unroll
            for (int j = 0; j < 4; ++j) b[j] = Bs[kk][cx * 4 + j];
#pragma unroll
            for (int i = 0; i < 4; ++i)
#pragma unroll
                for (int j = 0; j < 4; ++j)
                    acc[i][j] = fmaf(a[i], b[j], acc[i][j]);
        }
    }
    int colbase = bn + cx * 4;
    if (colbase < N) {
#pragma unroll
        for (int i = 0; i < 4; ++i) {
            int row = bm + ry * 4 + i;
            float4 o;
            float vv[4];
#pragma unroll
            for (int j = 0; j < 4; ++j) {
                float v = acc[i][j];
                if (EPI == 1) {
                    v += bias[colbase + j];
                    v = (v > 20.f) ? v : log1pf(__expf(v));
                }
                vv[j] = v;
            }
            o.x = vv[0]; o.y = vv[1]; o.z = vv[2]; o.w = vv[3];
            *(float4*)(C + (size_t)row * ldc + colbase) = o;
        }
    }
}

// ---------------- causal depthwise conv (k=4) + SiLU ----------------
// x = xz[:, :, :2048]; out[bl, d] = silu(sum_j w[d][j] * x[bl - 3 + j, d] + b[d])
__global__ __launch_bounds__(256) void conv_silu_kernel(const float* __restrict__ xz,
                                                        const float* __restrict__ cw,
                                                        const float* __restrict__ cb,
                                                        float* __restrict__ out) {
    int idx = blockIdx.x * 256 + threadIdx.x;      // (b*L + l) * D_INNER + d
    int d = idx & (D_INNER - 1);
    int l = (idx >> 11) & (LSEQ - 1);
    int bl = idx >> 11;
    const float* xcol = xz + (size_t)bl * (2 * D_INNER) + d;
    float w0 = cw[d * 4 + 0], w1 = cw[d * 4 + 1], w2 = cw[d * 4 + 2], w3 = cw[d * 4 + 3];
    float acc = cb[d];
    acc = fmaf(w3, xcol[0], acc);
    if (l >= 1) acc = fmaf(w2, xcol[-1 * (2 * D_INNER)], acc);
    if (l >= 2) acc = fmaf(w1, xcol[-2 * (2 * D_INNER)], acc);
    if (l >= 3) acc = fmaf(w0, xcol[-3 * (2 * D_INNER)], acc);
    float s = acc / (1.f + __expf(-acc));
    out[idx] = s;
}

// ---------------- selective scan (sequential over L), fused silu(z) gate ----------------
// One thread per (b, d) channel; 16 states in registers; B/C broadcast via LDS.
__global__ __launch_bounds__(256) void scan_kernel(const float* __restrict__ xp,
                                                   const float* __restrict__ delta,
                                                   const float* __restrict__ xc,
                                                   const float* __restrict__ xz,
                                                   const float* __restrict__ A_log,
                                                   const float* __restrict__ Dp,
                                                   float* __restrict__ y) {
    int b = blockIdx.x >> 3;
    int d = (blockIdx.x & 7) * 256 + threadIdx.x;
    float Av[D_STATE];
#pragma unroll
    for (int n = 0; n < D_STATE; ++n) Av[n] = -__expf(A_log[d * D_STATE + n]);
    float h[D_STATE] = {};
    float Dv = Dp[d];
    __shared__ float bc[32];
    for (int l = 0; l < LSEQ; ++l) {
        size_t r = (size_t)b * LSEQ + l;
        __syncthreads();
        if (threadIdx.x < 32) bc[threadIdx.x] = xp[r * XPN + DT_RANK + threadIdx.x];
        __syncthreads();
        float dv = delta[r * D_INNER + d];
        float u = xc[r * D_INNER + d];
        float du = dv * u;
        float acc = 0.f;
#pragma unroll
        for (int n = 0; n < D_STATE; ++n) {
            float dA = __expf(dv * Av[n]);
            h[n] = fmaf(dA, h[n], du * bc[n]);
            acc = fmaf(h[n], bc[D_STATE + n], acc);
        }
        float yv = fmaf(u, Dv, acc);
        float zv = xz[r * (2 * D_INNER) + D_INNER + d];
        float sz = zv / (1.f + __expf(-zv));
        y[r * D_INNER + d] = yv * sz;
    }
}

extern "C" void kernel_launch(void* const* d_in, const int* in_sizes, int n_in,
                              void* d_out, int out_size, void* d_ws, size_t ws_size,
                              hipStream_t stream) {
    const float* hidden = (const float*)d_in[0];
    const float* norm_w = (const float*)d_in[1];
    const float* norm_b = (const float*)d_in[2];
    const float* in_proj_w = (const float*)d_in[3];
    const float* conv_w = (const float*)d_in[4];
    const float* conv_b = (const float*)d_in[5];
    const float* x_proj_w = (const float*)d_in[6];
    const float* dt_proj_w = (const float*)d_in[7];
    const float* dt_proj_b = (const float*)d_in[8];
    const float* A_log = (const float*)d_in[9];
    const float* D_param = (const float*)d_in[10];
    const float* out_proj_w = (const float*)d_in[11];
    float* out = (float*)d_out;

    float* w = (float*)d_ws;
    float* hbuf = w;                          // 2048*1024  = 2,097,152
    float* xzbuf = hbuf + (size_t)NROWS * D_MODEL;        // 2048*4096 = 8,388,608
    float* xcbuf = xzbuf + (size_t)NROWS * 2 * D_INNER;   // 2048*2048 = 4,194,304
    float* dltbuf = xcbuf + (size_t)NROWS * D_INNER;      // 2048*2048 = 4,194,304
    float* xpbuf = hbuf;                      // reuse LN buffer after in_proj (needs 196,608)
    float* ybuf = dltbuf;                     // alias: scan reads delta[r,d] before writing y[r,d]

    // 1. LayerNorm
    ln_kernel<<<NROWS, 256, 0, stream>>>(hidden, norm_w, norm_b, hbuf);

    // 2. xz = h @ in_proj_w  (2048 x 4096 x K=1024)
    gemm_f32<0><<<dim3(2 * D_INNER / 64, NROWS / 64), 256, 0, stream>>>(
        hbuf, D_MODEL, in_proj_w, nullptr, xzbuf, 2 * D_INNER, NROWS, 2 * D_INNER, D_MODEL);

    // 3. conv + silu on x half
    conv_silu_kernel<<<(NROWS * D_INNER) / 256, 256, 0, stream>>>(xzbuf, conv_w, conv_b, xcbuf);

    // 4. xp = xc @ x_proj_w  (2048 x 96 x K=2048)
    gemm_f32<0><<<dim3((XPN + 63) / 64, NROWS / 64), 256, 0, stream>>>(
        xcbuf, D_INNER, x_proj_w, nullptr, xpbuf, XPN, NROWS, XPN, D_INNER);

    // 5. delta = softplus(dt_r @ dt_proj_w + dt_proj_b)  (2048 x 2048 x K=64)
    gemm_f32<1><<<dim3(D_INNER / 64, NROWS / 64), 256, 0, stream>>>(
        xpbuf, XPN, dt_proj_w, dt_proj_b, dltbuf, D_INNER, NROWS, D_INNER, DT_RANK);

    // 6. selective scan + silu(z) gate
    scan_kernel<<<NB * (D_INNER / 256), 256, 0, stream>>>(
        xpbuf, dltbuf, xcbuf, xzbuf, A_log, D_param, ybuf);

    // 7. out = y @ out_proj_w  (2048 x 1024 x K=2048)
    gemm_f32<0><<<dim3(D_MODEL / 64, NROWS / 64), 256, 0, stream>>>(
        ybuf, D_INNER, out_proj_w, nullptr, out, D_MODEL, NROWS, D_MODEL, D_INNER);
}

// Round 2
// 612.698 us; speedup vs baseline: 2.2215x; 2.2215x over previous
//
#include <hip/hip_runtime.h>
#include <hip/hip_bf16.h>

#define D_MODEL 1024
#define D_INNER 2048
#define D_STATE 16
#define D_CONV 4
#define DT_RANK 64
#define NB 2
#define LSEQ 1024
#define NROWS (NB * LSEQ)
#define XPN (DT_RANK + 2 * D_STATE) // 96
#define NC 32                       // chunks over L
#define CL 32                       // steps per chunk (NC*CL == LSEQ)

// Map a linear index into the dead x-half (cols 0..2047) of the xz buffer
// (row-major [2048][4096]); free after the conv consumes x.
__device__ __forceinline__ size_t xzmap(size_t i) {
    return ((i >> 11) << 12) + (i & 2047);
}

// ---------------- LayerNorm ----------------
__global__ __launch_bounds__(256) void ln_kernel(const float* __restrict__ x,
                                                 const float* __restrict__ w,
                                                 const float* __restrict__ bnorm,
                                                 float* __restrict__ out) {
    int row = blockIdx.x;
    const float4* xr = (const float4*)(x + (size_t)row * D_MODEL);
    float4 v = xr[threadIdx.x];
    float s = v.x + v.y + v.z + v.w;
    float sq = v.x * v.x + v.y * v.y + v.z * v.z + v.w * v.w;
#pragma unroll
    for (int off = 32; off > 0; off >>= 1) {
        s += __shfl_down(s, off);
        sq += __shfl_down(sq, off);
    }
    __shared__ float ws[4], wq[4];
    __shared__ float smu, srstd;
    int wave = threadIdx.x >> 6;
    if ((threadIdx.x & 63) == 0) { ws[wave] = s; wq[wave] = sq; }
    __syncthreads();
    if (threadIdx.x == 0) {
        float ts = ws[0] + ws[1] + ws[2] + ws[3];
        float tq = wq[0] + wq[1] + wq[2] + wq[3];
        float mu = ts * (1.f / D_MODEL);
        float var = tq * (1.f / D_MODEL) - mu * mu;
        smu = mu;
        srstd = rsqrtf(var + 1e-5f);
    }
    __syncthreads();
    float mu = smu, rstd = srstd;
    float4 wv = ((const float4*)w)[threadIdx.x];
    float4 bv = ((const float4*)bnorm)[threadIdx.x];
    float4 o;
    o.x = (v.x - mu) * rstd * wv.x + bv.x;
    o.y = (v.y - mu) * rstd * wv.y + bv.y;
    o.z = (v.z - mu) * rstd * wv.z + bv.z;
    o.w = (v.w - mu) * rstd * wv.w + bv.w;
    ((float4*)(out + (size_t)row * D_MODEL))[threadIdx.x] = o;
}

// ---------------- fp32 tiled GEMM ----------------
template <int EPI>
__global__ __launch_bounds__(256) void gemm_f32(const float* __restrict__ A, int lda,
                                                const float* __restrict__ Bw,
                                                const float* __restrict__ bias,
                                                float* __restrict__ C, int ldc,
                                                int M, int N, int K) {
    __shared__ float As[64][17];
    __shared__ float Bs[16][64];
    int tid = threadIdx.x;
    int cx = tid & 15, ry = tid >> 4;
    int bm = blockIdx.y * 64, bn = blockIdx.x * 64;
    int arow = tid >> 2, acol = (tid & 3) * 4;
    int brow = tid >> 4, bcol = (tid & 15) * 4;
    float acc[4][4] = {};
    for (int k0 = 0; k0 < K; k0 += 16) {
        float4 av = *(const float4*)(A + (size_t)(bm + arow) * lda + (k0 + acol));
        float4 bv = make_float4(0.f, 0.f, 0.f, 0.f);
        if (bn + bcol < N)
            bv = *(const float4*)(Bw + (size_t)(k0 + brow) * N + (bn + bcol));
        __syncthreads();
        As[arow][acol] = av.x; As[arow][acol + 1] = av.y;
        As[arow][acol + 2] = av.z; As[arow][acol + 3] = av.w;
        *(float4*)&Bs[brow][bcol] = bv;
        __syncthreads();
#pragma unroll
        for (int kk = 0; kk < 16; ++kk) {
            float a[4], b[4];
#pragma unroll
            for (int i = 0; i < 4; ++i) a[i] = As[ry * 4 + i][kk];
#pragma unroll
            for (int j = 0; j < 4; ++j) b[j] = Bs[kk][cx * 4 + j];
#pragma unroll
            for (int i = 0; i < 4; ++i)
#pragma unroll
                for (int j = 0; j < 4; ++j)
                    acc[i][j] = fmaf(a[i], b[j], acc[i][j]);
        }
    }
    int colbase = bn + cx * 4;
    if (colbase < N) {
#pragma unroll
        for (int i = 0; i < 4; ++i) {
            int row = bm + ry * 4 + i;
            float4 o;
            float vv[4];
#pragma unroll
            for (int j = 0; j < 4; ++j) {
                float v = acc[i][j];
                if (EPI == 1) {
                    v += bias[colbase + j];
                    v = (v > 20.f) ? v : log1pf(__expf(v));
                }
                vv[j] = v;
            }
            o.x = vv[0]; o.y = vv[1]; o.z = vv[2]; o.w = vv[3];
            *(float4*)(C + (size_t)row * ldc + colbase) = o;
        }
    }
}

// ---------------- causal depthwise conv (k=4) + SiLU ----------------
__global__ __launch_bounds__(256) void conv_silu_kernel(const float* __restrict__ xz,
                                                        const float* __restrict__ cw,
                                                        const float* __restrict__ cb,
                                                        float* __restrict__ out) {
    int idx = blockIdx.x * 256 + threadIdx.x;
    int d = idx & (D_INNER - 1);
    int l = (idx >> 11) & (LSEQ - 1);
    int bl = idx >> 11;
    const float* xcol = xz + (size_t)bl * (2 * D_INNER) + d;
    float w0 = cw[d * 4 + 0], w1 = cw[d * 4 + 1], w2 = cw[d * 4 + 2], w3 = cw[d * 4 + 3];
    float acc = cb[d];
    acc = fmaf(w3, xcol[0], acc);
    if (l >= 1) acc = fmaf(w2, xcol[-1 * (2 * D_INNER)], acc);
    if (l >= 2) acc = fmaf(w1, xcol[-2 * (2 * D_INNER)], acc);
    if (l >= 3) acc = fmaf(w0, xcol[-3 * (2 * D_INNER)], acc);
    float s = acc / (1.f + __expf(-acc));
    out[idx] = s;
}

// ---------------- scan phase 1: per-chunk local scan (h0 = 0) ----------------
// grid: (NB*NC) * 8 blocks of 256. Writes hout[c][b][d][0:16] (in xz x-half) and sdel.
__global__ __launch_bounds__(256) void scan_local(const float* __restrict__ xp,
                                                  const float* __restrict__ delta,
                                                  const float* __restrict__ xc,
                                                  const float* __restrict__ A_log,
                                                  float* __restrict__ xzh,
                                                  float* __restrict__ sdel) {
    int bc = blockIdx.x >> 3;
    int b = bc >> 5, c = bc & (NC - 1);
    int d = (blockIdx.x & 7) * 256 + threadIdx.x;
    int base_r = b * LSEQ + c * CL;
    __shared__ float Bs[CL * 16];
    for (int e = threadIdx.x; e < CL * 16; e += 256) {
        int l = e >> 4, n = e & 15;
        Bs[e] = xp[(size_t)(base_r + l) * XPN + DT_RANK + n];
    }
    __syncthreads();
    float Av[16];
    const float4* ap = (const float4*)(A_log + (size_t)d * 16);
#pragma unroll
    for (int q = 0; q < 4; ++q) {
        float4 a = ap[q];
        Av[4 * q + 0] = -__expf(a.x); Av[4 * q + 1] = -__expf(a.y);
        Av[4 * q + 2] = -__expf(a.z); Av[4 * q + 3] = -__expf(a.w);
    }
    float h[16] = {};
    float sd = 0.f;
    const float* dp = delta + (size_t)base_r * D_INNER + d;
    const float* up = xc + (size_t)base_r * D_INNER + d;
#pragma unroll 4
    for (int l = 0; l < CL; ++l) {
        float dv = dp[(size_t)l * D_INNER];
        float u = up[(size_t)l * D_INNER];
        float du = dv * u;
        sd += dv;
#pragma unroll
        for (int n = 0; n < 16; ++n) {
            float dA = __expf(dv * Av[n]);
            h[n] = fmaf(dA, h[n], du * Bs[l * 16 + n]);
        }
    }
    size_t hi = ((size_t)(c * NB + b) * D_INNER + d) * 16;
#pragma unroll
    for (int q = 0; q < 4; ++q) {
        float4 v = make_float4(h[4 * q], h[4 * q + 1], h[4 * q + 2], h[4 * q + 3]);
        *(float4*)(xzh + xzmap(hi + 4 * q)) = v;
    }
    sdel[(size_t)(c * NB + b) * D_INNER + d] = sd;
}

// ---------------- scan phase 2: cross-chunk combine ----------------
// One thread per (b,d,n). Replaces hout[c] (local out) with Hin[c] (incoming state).
__global__ __launch_bounds__(256) void scan_combine(const float* __restrict__ A_log,
                                                    const float* __restrict__ sdel,
                                                    float* __restrict__ xzh) {
    int t = blockIdx.x * 256 + threadIdx.x;
    int n = t & 15, d = (t >> 4) & (D_INNER - 1), b = t >> 15;
    float Avn = -__expf(A_log[(size_t)d * 16 + n]);
    float h = 0.f;
#pragma unroll 4
    for (int c = 0; c < NC; ++c) {
        size_t base = (size_t)(c * NB + b) * D_INNER + d;
        float S = sdel[base];
        float* hp = xzh + xzmap(base * 16 + n);
        float tmp = *hp;
        *hp = h;
        h = fmaf(__expf(Avn * S), h, tmp);
    }
}

// ---------------- scan phase 3: finalize with true h_in, fuse gate ----------------
__global__ __launch_bounds__(256) void scan_final(const float* __restrict__ xp,
                                                  float* dlt_y,  // delta in, y out (aliased)
                                                  const float* __restrict__ xc,
                                                  const float* __restrict__ xz,
                                                  const float* __restrict__ A_log,
                                                  const float* __restrict__ Dp) {
    int bc = blockIdx.x >> 3;
    int b = bc >> 5, c = bc & (NC - 1);
    int d = (blockIdx.x & 7) * 256 + threadIdx.x;
    int base_r = b * LSEQ + c * CL;
    __shared__ float Bs[CL * 16], Cs[CL * 16];
    for (int e = threadIdx.x; e < CL * 16; e += 256) {
        int l = e >> 4, n = e & 15;
        Bs[e] = xp[(size_t)(base_r + l) * XPN + DT_RANK + n];
        Cs[e] = xp[(size_t)(base_r + l) * XPN + DT_RANK + 16 + n];
    }
    __syncthreads();
    float Av[16];
    const float4* ap = (const float4*)(A_log + (size_t)d * 16);
#pragma unroll
    for (int q = 0; q < 4; ++q) {
        float4 a = ap[q];
        Av[4 * q + 0] = -__expf(a.x); Av[4 * q + 1] = -__expf(a.y);
        Av[4 * q + 2] = -__expf(a.z); Av[4 * q + 3] = -__expf(a.w);
    }
    float h[16];
    size_t hi = ((size_t)(c * NB + b) * D_INNER + d) * 16;
#pragma unroll
    for (int q = 0; q < 4; ++q) {
        float4 v = *(const float4*)(xz + xzmap(hi + 4 * q));
        h[4 * q] = v.x; h[4 * q + 1] = v.y; h[4 * q + 2] = v.z; h[4 * q + 3] = v.w;
    }
    float Dv = Dp[d];
    float* dyp = dlt_y + (size_t)base_r * D_INNER + d;
    const float* up = xc + (size_t)base_r * D_INNER + d;
    const float* zp = xz + (size_t)base_r * (2 * D_INNER) + D_INNER + d;
#pragma unroll 4
    for (int l = 0; l < CL; ++l) {
        float dv = dyp[(size_t)l * D_INNER];
        float u = up[(size_t)l * D_INNER];
        float du = dv * u;
        float acc = 0.f;
#pragma unroll
        for (int n = 0; n < 16; ++n) {
            float dA = __expf(dv * Av[n]);
            h[n] = fmaf(dA, h[n], du * Bs[l * 16 + n]);
            acc = fmaf(h[n], Cs[l * 16 + n], acc);
        }
        float yv = fmaf(u, Dv, acc);
        float zv = zp[(size_t)l * (2 * D_INNER)];
        float sz = zv / (1.f + __expf(-zv));
        dyp[(size_t)l * D_INNER] = yv * sz;
    }
}

extern "C" void kernel_launch(void* const* d_in, const int* in_sizes, int n_in,
                              void* d_out, int out_size, void* d_ws, size_t ws_size,
                              hipStream_t stream) {
    const float* hidden = (const float*)d_in[0];
    const float* norm_w = (const float*)d_in[1];
    const float* norm_b = (const float*)d_in[2];
    const float* in_proj_w = (const float*)d_in[3];
    const float* conv_w = (const float*)d_in[4];
    const float* conv_b = (const float*)d_in[5];
    const float* x_proj_w = (const float*)d_in[6];
    const float* dt_proj_w = (const float*)d_in[7];
    const float* dt_proj_b = (const float*)d_in[8];
    const float* A_log = (const float*)d_in[9];
    const float* D_param = (const float*)d_in[10];
    const float* out_proj_w = (const float*)d_in[11];
    float* out = (float*)d_out;

    float* w = (float*)d_ws;
    float* hbuf = w;                                      // 2,097,152 floats
    float* xzbuf = hbuf + (size_t)NROWS * D_MODEL;        // 8,388,608
    float* xcbuf = xzbuf + (size_t)NROWS * 2 * D_INNER;   // 4,194,304
    float* dltbuf = xcbuf + (size_t)NROWS * D_INNER;      // 4,194,304
    float* xpbuf = hbuf;                                  // reuse (196,608 floats)
    float* sdelbuf = hbuf + 262144;                       // 131,072 floats (dead region)
    float* ybuf = dltbuf;                                 // alias (read-then-write per elem)

    // 1. LayerNorm
    ln_kernel<<<NROWS, 256, 0, stream>>>(hidden, norm_w, norm_b, hbuf);

    // 2. xz = h @ in_proj_w
    gemm_f32<0><<<dim3(2 * D_INNER / 64, NROWS / 64), 256, 0, stream>>>(
        hbuf, D_MODEL, in_proj_w, nullptr, xzbuf, 2 * D_INNER, NROWS, 2 * D_INNER, D_MODEL);

    // 3. conv + silu
    conv_silu_kernel<<<(NROWS * D_INNER) / 256, 256, 0, stream>>>(xzbuf, conv_w, conv_b, xcbuf);

    // 4. xp = xc @ x_proj_w
    gemm_f32<0><<<dim3((XPN + 63) / 64, NROWS / 64), 256, 0, stream>>>(
        xcbuf, D_INNER, x_proj_w, nullptr, xpbuf, XPN, NROWS, XPN, D_INNER);

    // 5. delta = softplus(dt_r @ dt_proj_w + b)
    gemm_f32<1><<<dim3(D_INNER / 64, NROWS / 64), 256, 0, stream>>>(
        xpbuf, XPN, dt_proj_w, dt_proj_b, dltbuf, D_INNER, NROWS, D_INNER, DT_RANK);

    // 6. chunked selective scan (3 phases) + fused silu(z) gate
    scan_local<<<NB * NC * (D_INNER / 256), 256, 0, stream>>>(
        xpbuf, dltbuf, xcbuf, A_log, xzbuf, sdelbuf);
    scan_combine<<<(NB * D_INNER * D_STATE) / 256, 256, 0, stream>>>(
        A_log, sdelbuf, xzbuf);
    scan_final<<<NB * NC * (D_INNER / 256), 256, 0, stream>>>(
        xpbuf, dltbuf, xcbuf, xzbuf, A_log, D_param);

    // 7. out = y @ out_proj_w
    gemm_f32<0><<<dim3(D_MODEL / 64, NROWS / 64), 256, 0, stream>>>(
        ybuf, D_INNER, out_proj_w, nullptr, out, D_MODEL, NROWS, D_MODEL, D_INNER);
}

// Round 3
// 209.645 us; speedup vs baseline: 6.4924x; 2.9225x over previous
//
#include <hip/hip_runtime.h>
#include <hip/hip_bf16.h>

#define D_MODEL 1024
#define D_INNER 2048
#define D_STATE 16
#define DT_RANK 64
#define NB 2
#define LSEQ 1024
#define NROWS (NB * LSEQ)
#define XPN 96
#define NC 32
#define CL 32

typedef __attribute__((ext_vector_type(8))) short bf16x8;
typedef __attribute__((ext_vector_type(4))) float f32x4;

__device__ __forceinline__ unsigned short f2bf(float x) {
    __hip_bfloat16 h = __float2bfloat16(x);
    return *reinterpret_cast<unsigned short*>(&h);
}

// Map a linear index into the dead x-half (cols 0..2047) of the xz buffer
__device__ __forceinline__ size_t xzmap(size_t i) {
    return ((i >> 11) << 12) + (i & 2047);
}

// ---------------- LayerNorm -> bf16 out ----------------
__global__ __launch_bounds__(256) void ln_kernel(const float* __restrict__ x,
                                                 const float* __restrict__ w,
                                                 const float* __restrict__ bnorm,
                                                 unsigned short* __restrict__ outb) {
    int row = blockIdx.x;
    const float4* xr = (const float4*)(x + (size_t)row * D_MODEL);
    float4 v = xr[threadIdx.x];
    float s = v.x + v.y + v.z + v.w;
    float sq = v.x * v.x + v.y * v.y + v.z * v.z + v.w * v.w;
#pragma unroll
    for (int off = 32; off > 0; off >>= 1) {
        s += __shfl_down(s, off);
        sq += __shfl_down(sq, off);
    }
    __shared__ float ws[4], wq[4];
    __shared__ float smu, srstd;
    int wave = threadIdx.x >> 6;
    if ((threadIdx.x & 63) == 0) { ws[wave] = s; wq[wave] = sq; }
    __syncthreads();
    if (threadIdx.x == 0) {
        float ts = ws[0] + ws[1] + ws[2] + ws[3];
        float tq = wq[0] + wq[1] + wq[2] + wq[3];
        float mu = ts * (1.f / D_MODEL);
        float var = tq * (1.f / D_MODEL) - mu * mu;
        smu = mu;
        srstd = rsqrtf(var + 1e-5f);
    }
    __syncthreads();
    float mu = smu, rstd = srstd;
    float4 wv = ((const float4*)w)[threadIdx.x];
    float4 bv = ((const float4*)bnorm)[threadIdx.x];
    ushort4 pk;
    pk.x = f2bf((v.x - mu) * rstd * wv.x + bv.x);
    pk.y = f2bf((v.y - mu) * rstd * wv.y + bv.y);
    pk.z = f2bf((v.z - mu) * rstd * wv.z + bv.z);
    pk.w = f2bf((v.w - mu) * rstd * wv.w + bv.w);
    *(ushort4*)(outb + (size_t)row * D_MODEL + threadIdx.x * 4) = pk;
}

// ---------------- weight cast + transpose: W[K][Nreal] f32 -> Wt[Npad][K] bf16 ----------------
__global__ __launch_bounds__(256) void wcast_t(const float* __restrict__ W,
                                               unsigned short* __restrict__ Wt,
                                               int K, int Nreal, int Npad) {
    __shared__ float t[32][33];
    int tn = blockIdx.x * 32, tk = blockIdx.y * 32;
    for (int e = threadIdx.x; e < 1024; e += 256) {
        int r = e >> 5, c = e & 31;                 // r: k-off, c: n-off
        int n = tn + c;
        t[r][c] = (n < Nreal) ? W[(size_t)(tk + r) * Nreal + n] : 0.f;
    }
    __syncthreads();
    for (int e = threadIdx.x; e < 1024; e += 256) {
        int r = e >> 5, c = e & 31;                 // r: n-off, c: k-off
        Wt[(size_t)(tn + r) * K + tk + c] = f2bf(t[c][r]);
    }
}

// ---------------- bf16 MFMA GEMM (m97 structure): C = A[M][K] @ Bt[N][K]^T ----------------
// 128x128 tile, BK=32, 256 thr (4 waves 2x2, 64x64 each), global_load_lds staging.
// grid (N/128, M/128, KS). KS>1 -> writes partials at C + z*M*ldc (caller reduces).
__global__ __launch_bounds__(256) void gemm_bf16(const unsigned short* __restrict__ A,
                                                 const unsigned short* __restrict__ Bt,
                                                 float* __restrict__ C,
                                                 int M, int K, int ldc, int Nreal) {
    __shared__ unsigned short As[128 * 32];
    __shared__ unsigned short Bs[128 * 32];
    int tid = threadIdx.x;
    int lane = tid & 63;
    int wave = tid >> 6;
    int wr = (wave >> 1) * 64, wc = (wave & 1) * 64;
    int bm = blockIdx.y * 128, bn = blockIdx.x * 128;
    int kchunk = K / gridDim.z;
    int kbeg = blockIdx.z * kchunk;

    f32x4 acc[4][4];
#pragma unroll
    for (int i = 0; i < 4; ++i)
#pragma unroll
        for (int j = 0; j < 4; ++j) acc[i][j] = (f32x4){0.f, 0.f, 0.f, 0.f};

    int r0 = tid >> 2;             // staging row within 64-row half
    int c0 = (tid & 3) * 8;        // staging k-offset (elements)
    const unsigned short* a0 = A + (size_t)(bm + r0) * K + c0;
    const unsigned short* a1 = A + (size_t)(bm + 64 + r0) * K + c0;
    const unsigned short* b0 = Bt + (size_t)(bn + r0) * K + c0;
    const unsigned short* b1 = Bt + (size_t)(bn + 64 + r0) * K + c0;
    unsigned short* asw0 = As + (size_t)(tid & ~63) * 8;
    unsigned short* asw1 = As + 2048 + (size_t)(tid & ~63) * 8;
    unsigned short* bsw0 = Bs + (size_t)(tid & ~63) * 8;
    unsigned short* bsw1 = Bs + 2048 + (size_t)(tid & ~63) * 8;

    int ar = lane & 15;
    int ko = (lane >> 4) * 8;

    for (int k0 = kbeg; k0 < kbeg + kchunk; k0 += 32) {
        __syncthreads();
        __builtin_amdgcn_global_load_lds((const __attribute__((address_space(1))) void*)(a0 + k0),
                                         (__attribute__((address_space(3))) void*)asw0, 16, 0, 0);
        __builtin_amdgcn_global_load_lds((const __attribute__((address_space(1))) void*)(a1 + k0),
                                         (__attribute__((address_space(3))) void*)asw1, 16, 0, 0);
        __builtin_amdgcn_global_load_lds((const __attribute__((address_space(1))) void*)(b0 + k0),
                                         (__attribute__((address_space(3))) void*)bsw0, 16, 0, 0);
        __builtin_amdgcn_global_load_lds((const __attribute__((address_space(1))) void*)(b1 + k0),
                                         (__attribute__((address_space(3))) void*)bsw1, 16, 0, 0);
        __syncthreads();
        bf16x8 af[4], bfr[4];
#pragma unroll
        for (int i = 0; i < 4; ++i)
            af[i] = *(const bf16x8*)&As[(size_t)(wr + i * 16 + ar) * 32 + ko];
#pragma unroll
        for (int j = 0; j < 4; ++j)
            bfr[j] = *(const bf16x8*)&Bs[(size_t)(wc + j * 16 + ar) * 32 + ko];
#pragma unroll
        for (int i = 0; i < 4; ++i)
#pragma unroll
            for (int j = 0; j < 4; ++j)
                acc[i][j] = __builtin_amdgcn_mfma_f32_16x16x32_bf16(af[i], bfr[j], acc[i][j], 0, 0, 0);
    }

    int crow0 = bm + wr + (lane >> 4) * 4;
    int ccol0 = bn + wc + (lane & 15);
    size_t zoff = (size_t)blockIdx.z * (size_t)M * ldc;
#pragma unroll
    for (int i = 0; i < 4; ++i)
#pragma unroll
        for (int j = 0; j < 4; ++j) {
            int col = ccol0 + j * 16;
            if (col < Nreal) {
                float* cp = C + zoff + (size_t)(crow0 + i * 16) * ldc + col;
#pragma unroll
                for (int r = 0; r < 4; ++r) cp[(size_t)r * ldc] = acc[i][j][r];
            }
        }
}

// ---------------- split-K reduce for xp ----------------
__global__ __launch_bounds__(256) void reduce_xp(const float* __restrict__ part,
                                                 float* __restrict__ xp) {
    int t = blockIdx.x * 256 + threadIdx.x;
    float s = 0.f;
#pragma unroll
    for (int k = 0; k < 8; ++k) s += part[(size_t)k * (NROWS * XPN) + t];
    xp[t] = s;
}

// ---------------- fp32 tiled GEMM (dt_proj only, K=64) ----------------
template <int EPI>
__global__ __launch_bounds__(256) void gemm_f32(const float* __restrict__ A, int lda,
                                                const float* __restrict__ Bw,
                                                const float* __restrict__ bias,
                                                float* __restrict__ C, int ldc,
                                                int M, int N, int K) {
    __shared__ float As[64][17];
    __shared__ float Bs[16][64];
    int tid = threadIdx.x;
    int cx = tid & 15, ry = tid >> 4;
    int bm = blockIdx.y * 64, bn = blockIdx.x * 64;
    int arow = tid >> 2, acol = (tid & 3) * 4;
    int brow = tid >> 4, bcol = (tid & 15) * 4;
    float acc[4][4] = {};
    for (int k0 = 0; k0 < K; k0 += 16) {
        float4 av = *(const float4*)(A + (size_t)(bm + arow) * lda + (k0 + acol));
        float4 bv = *(const float4*)(Bw + (size_t)(k0 + brow) * N + (bn + bcol));
        __syncthreads();
        As[arow][acol] = av.x; As[arow][acol + 1] = av.y;
        As[arow][acol + 2] = av.z; As[arow][acol + 3] = av.w;
        *(float4*)&Bs[brow][bcol] = bv;
        __syncthreads();
#pragma unroll
        for (int kk = 0; kk < 16; ++kk) {
            float a[4], b[4];
#pragma unroll
            for (int i = 0; i < 4; ++i) a[i] = As[ry * 4 + i][kk];
#pragma unroll
            for (int j = 0; j < 4; ++j) b[j] = Bs[kk][cx * 4 + j];
#pragma unroll
            for (int i = 0; i < 4; ++i)
#pragma unroll
                for (int j = 0; j < 4; ++j)
                    acc[i][j] = fmaf(a[i], b[j], acc[i][j]);
        }
    }
    int colbase = bn + cx * 4;
#pragma unroll
    for (int i = 0; i < 4; ++i) {
        int row = bm + ry * 4 + i;
        float vv[4];
#pragma unroll
        for (int j = 0; j < 4; ++j) {
            float v = acc[i][j];
            if (EPI == 1) {
                v += bias[colbase + j];
                v = (v > 20.f) ? v : log1pf(__expf(v));
            }
            vv[j] = v;
        }
        float4 o; o.x = vv[0]; o.y = vv[1]; o.z = vv[2]; o.w = vv[3];
        *(float4*)(C + (size_t)row * ldc + colbase) = o;
    }
}

// ---------------- causal depthwise conv (k=4) + SiLU -> f32 + bf16 ----------------
__global__ __launch_bounds__(256) void conv_silu_kernel(const float* __restrict__ xz,
                                                        const float* __restrict__ cw,
                                                        const float* __restrict__ cb,
                                                        float* __restrict__ out,
                                                        unsigned short* __restrict__ outb) {
    int idx = blockIdx.x * 256 + threadIdx.x;
    int d = idx & (D_INNER - 1);
    int l = (idx >> 11) & (LSEQ - 1);
    int bl = idx >> 11;
    const float* xcol = xz + (size_t)bl * (2 * D_INNER) + d;
    float w0 = cw[d * 4 + 0], w1 = cw[d * 4 + 1], w2 = cw[d * 4 + 2], w3 = cw[d * 4 + 3];
    float acc = cb[d];
    acc = fmaf(w3, xcol[0], acc);
    if (l >= 1) acc = fmaf(w2, xcol[-1 * (2 * D_INNER)], acc);
    if (l >= 2) acc = fmaf(w1, xcol[-2 * (2 * D_INNER)], acc);
    if (l >= 3) acc = fmaf(w0, xcol[-3 * (2 * D_INNER)], acc);
    float s = acc / (1.f + __expf(-acc));
    out[idx] = s;
    outb[idx] = f2bf(s);
}

// ---------------- scan phase 1: per-chunk local scan (h0 = 0) ----------------
__global__ __launch_bounds__(256) void scan_local(const float* __restrict__ xp,
                                                  const float* __restrict__ delta,
                                                  const float* __restrict__ xc,
                                                  const float* __restrict__ A_log,
                                                  float* __restrict__ xzh,
                                                  float* __restrict__ sdel) {
    int bc = blockIdx.x >> 3;
    int b = bc >> 5, c = bc & (NC - 1);
    int d = (blockIdx.x & 7) * 256 + threadIdx.x;
    int base_r = b * LSEQ + c * CL;
    __shared__ float Bs[CL * 16];
    for (int e = threadIdx.x; e < CL * 16; e += 256) {
        int l = e >> 4, n = e & 15;
        Bs[e] = xp[(size_t)(base_r + l) * XPN + DT_RANK + n];
    }
    __syncthreads();
    float Av[16];
    const float4* ap = (const float4*)(A_log + (size_t)d * 16);
#pragma unroll
    for (int q = 0; q < 4; ++q) {
        float4 a = ap[q];
        Av[4 * q + 0] = -__expf(a.x); Av[4 * q + 1] = -__expf(a.y);
        Av[4 * q + 2] = -__expf(a.z); Av[4 * q + 3] = -__expf(a.w);
    }
    float h[16] = {};
    float sd = 0.f;
    const float* dp = delta + (size_t)base_r * D_INNER + d;
    const float* up = xc + (size_t)base_r * D_INNER + d;
#pragma unroll 4
    for (int l = 0; l < CL; ++l) {
        float dv = dp[(size_t)l * D_INNER];
        float u = up[(size_t)l * D_INNER];
        float du = dv * u;
        sd += dv;
#pragma unroll
        for (int n = 0; n < 16; ++n) {
            float dA = __expf(dv * Av[n]);
            h[n] = fmaf(dA, h[n], du * Bs[l * 16 + n]);
        }
    }
    size_t hi = ((size_t)(c * NB + b) * D_INNER + d) * 16;
#pragma unroll
    for (int q = 0; q < 4; ++q) {
        float4 v = make_float4(h[4 * q], h[4 * q + 1], h[4 * q + 2], h[4 * q + 3]);
        *(float4*)(xzh + xzmap(hi + 4 * q)) = v;
    }
    sdel[(size_t)(c * NB + b) * D_INNER + d] = sd;
}

// ---------------- scan phase 2: cross-chunk combine ----------------
__global__ __launch_bounds__(256) void scan_combine(const float* __restrict__ A_log,
                                                    const float* __restrict__ sdel,
                                                    float* __restrict__ xzh) {
    int t = blockIdx.x * 256 + threadIdx.x;
    int n = t & 15, d = (t >> 4) & (D_INNER - 1), b = t >> 15;
    float Avn = -__expf(A_log[(size_t)d * 16 + n]);
    float h = 0.f;
#pragma unroll 4
    for (int c = 0; c < NC; ++c) {
        size_t base = (size_t)(c * NB + b) * D_INNER + d;
        float S = sdel[base];
        float* hp = xzh + xzmap(base * 16 + n);
        float tmp = *hp;
        *hp = h;
        h = fmaf(__expf(Avn * S), h, tmp);
    }
}

// ---------------- scan phase 3: finalize, fuse silu(z) gate -> bf16 y ----------------
__global__ __launch_bounds__(256) void scan_final(const float* __restrict__ xp,
                                                  const float* __restrict__ dlt,
                                                  const float* __restrict__ xc,
                                                  const float* __restrict__ xz,
                                                  const float* __restrict__ A_log,
                                                  const float* __restrict__ Dp,
                                                  unsigned short* __restrict__ yb) {
    int bc = blockIdx.x >> 3;
    int b = bc >> 5, c = bc & (NC - 1);
    int d = (blockIdx.x & 7) * 256 + threadIdx.x;
    int base_r = b * LSEQ + c * CL;
    __shared__ float Bs[CL * 16], Cs[CL * 16];
    for (int e = threadIdx.x; e < CL * 16; e += 256) {
        int l = e >> 4, n = e & 15;
        Bs[e] = xp[(size_t)(base_r + l) * XPN + DT_RANK + n];
        Cs[e] = xp[(size_t)(base_r + l) * XPN + DT_RANK + 16 + n];
    }
    __syncthreads();
    float Av[16];
    const float4* ap = (const float4*)(A_log + (size_t)d * 16);
#pragma unroll
    for (int q = 0; q < 4; ++q) {
        float4 a = ap[q];
        Av[4 * q + 0] = -__expf(a.x); Av[4 * q + 1] = -__expf(a.y);
        Av[4 * q + 2] = -__expf(a.z); Av[4 * q + 3] = -__expf(a.w);
    }
    float h[16];
    size_t hi = ((size_t)(c * NB + b) * D_INNER + d) * 16;
#pragma unroll
    for (int q = 0; q < 4; ++q) {
        float4 v = *(const float4*)(xz + xzmap(hi + 4 * q));
        h[4 * q] = v.x; h[4 * q + 1] = v.y; h[4 * q + 2] = v.z; h[4 * q + 3] = v.w;
    }
    float Dv = Dp[d];
    const float* dyp = dlt + (size_t)base_r * D_INNER + d;
    const float* up = xc + (size_t)base_r * D_INNER + d;
    const float* zp = xz + (size_t)base_r * (2 * D_INNER) + D_INNER + d;
#pragma unroll 4
    for (int l = 0; l < CL; ++l) {
        float dv = dyp[(size_t)l * D_INNER];
        float u = up[(size_t)l * D_INNER];
        float du = dv * u;
        float acc = 0.f;
#pragma unroll
        for (int n = 0; n < 16; ++n) {
            float dA = __expf(dv * Av[n]);
            h[n] = fmaf(dA, h[n], du * Bs[l * 16 + n]);
            acc = fmaf(h[n], Cs[l * 16 + n], acc);
        }
        float yv = fmaf(u, Dv, acc);
        float zv = zp[(size_t)l * (2 * D_INNER)];
        float sz = zv / (1.f + __expf(-zv));
        yb[(size_t)(base_r + l) * D_INNER + d] = f2bf(yv * sz);
    }
}

extern "C" void kernel_launch(void* const* d_in, const int* in_sizes, int n_in,
                              void* d_out, int out_size, void* d_ws, size_t ws_size,
                              hipStream_t stream) {
    const float* hidden = (const float*)d_in[0];
    const float* norm_w = (const float*)d_in[1];
    const float* norm_b = (const float*)d_in[2];
    const float* in_proj_w = (const float*)d_in[3];
    const float* conv_w = (const float*)d_in[4];
    const float* conv_b = (const float*)d_in[5];
    const float* x_proj_w = (const float*)d_in[6];
    const float* dt_proj_w = (const float*)d_in[7];
    const float* dt_proj_b = (const float*)d_in[8];
    const float* A_log = (const float*)d_in[9];
    const float* D_param = (const float*)d_in[10];
    const float* out_proj_w = (const float*)d_in[11];
    float* out = (float*)d_out;

    float* wsf = (float*)d_ws;
    // region 0: [0 .. 1,048,576) floats — time-shared:
    unsigned short* hbufb = (unsigned short*)wsf;          // LN out bf16 [2048][1024]
    float* xpbuf = wsf;                                    // xp f32 [2048][96] (after in_proj)
    float* sdelbuf = wsf + 196608;                         // [64][2048]
    unsigned short* wOt = (unsigned short*)wsf;            // out_proj_w^T bf16 [1024][2048] (after scan)
    float* xzbuf = wsf + 1048576;                          // f32 [2048][4096]
    float* xcbuf = xzbuf + 8388608;                        // f32 [2048][2048]
    unsigned short* xcb = (unsigned short*)(xcbuf + 4194304); // conv out bf16 [2048][2048]
    unsigned short* yb = xcb;                              // y bf16 (after x_proj)
    float* dltbuf = xcbuf + 4194304 + 2097152;             // f32 [2048][2048] — time-shared:
    unsigned short* wAt = (unsigned short*)dltbuf;         //   in_proj_w^T bf16 [4096][1024]
    float* xpart = dltbuf;                                 //   x_proj split-K partials [8][2048][96]
    unsigned short* wXt = (unsigned short*)(dltbuf + 2097152); // x_proj_w^T bf16 padded [128][2048]

    // 1-2. weight casts (transposed, bf16)
    wcast_t<<<dim3(4096 / 32, 1024 / 32), 256, 0, stream>>>(in_proj_w, wAt, 1024, 4096, 4096);
    wcast_t<<<dim3(128 / 32, 2048 / 32), 256, 0, stream>>>(x_proj_w, wXt, 2048, 96, 128);

    // 3. LayerNorm -> bf16
    ln_kernel<<<NROWS, 256, 0, stream>>>(hidden, norm_w, norm_b, hbufb);

    // 4. xz = h @ in_proj_w  (MFMA bf16)
    gemm_bf16<<<dim3(4096 / 128, NROWS / 128, 1), 256, 0, stream>>>(
        hbufb, wAt, xzbuf, NROWS, 1024, 4096, 4096);

    // 5. conv + silu -> f32 + bf16
    conv_silu_kernel<<<(NROWS * D_INNER) / 256, 256, 0, stream>>>(xzbuf, conv_w, conv_b, xcbuf, xcb);

    // 6. xp partials = xc @ x_proj_w  (MFMA bf16, split-K=8)
    gemm_bf16<<<dim3(1, NROWS / 128, 8), 256, 0, stream>>>(
        xcb, wXt, xpart, NROWS, 2048, XPN, XPN);

    // 7. reduce partials -> xp f32
    reduce_xp<<<(NROWS * XPN) / 256, 256, 0, stream>>>(xpart, xpbuf);

    // 8. delta = softplus(dt_r @ dt_proj_w + b)  (fp32)
    gemm_f32<1><<<dim3(D_INNER / 64, NROWS / 64), 256, 0, stream>>>(
        xpbuf, XPN, dt_proj_w, dt_proj_b, dltbuf, D_INNER, NROWS, D_INNER, DT_RANK);

    // 9-11. chunked selective scan + fused gate -> bf16 y
    scan_local<<<NB * NC * (D_INNER / 256), 256, 0, stream>>>(
        xpbuf, dltbuf, xcbuf, A_log, xzbuf, sdelbuf);
    scan_combine<<<(NB * D_INNER * D_STATE) / 256, 256, 0, stream>>>(
        A_log, sdelbuf, xzbuf);
    scan_final<<<NB * NC * (D_INNER / 256), 256, 0, stream>>>(
        xpbuf, dltbuf, xcbuf, xzbuf, A_log, D_param, yb);

    // 12. out_proj weight cast (region 0 is dead now)
    wcast_t<<<dim3(1024 / 32, 2048 / 32), 256, 0, stream>>>(out_proj_w, wOt, 2048, 1024, 1024);

    // 13. out = y @ out_proj_w  (MFMA bf16)
    gemm_bf16<<<dim3(1024 / 128, NROWS / 128, 1), 256, 0, stream>>>(
        yb, wOt, out, NROWS, 2048, 1024, 1024);
}

// Round 4
// 199.902 us; speedup vs baseline: 6.8088x; 1.0487x over previous
//
#include <hip/hip_runtime.h>
#include <hip/hip_bf16.h>

#define D_MODEL 1024
#define D_INNER 2048
#define D_STATE 16
#define DT_RANK 64
#define NB 2
#define LSEQ 1024
#define NROWS (NB * LSEQ)
#define XPN 96
#define NC 32
#define CL 32

typedef __attribute__((ext_vector_type(8))) short bf16x8;
typedef __attribute__((ext_vector_type(4))) float f32x4;

__device__ __forceinline__ unsigned short f2bf(float x) {
    __hip_bfloat16 h = __float2bfloat16(x);
    return *reinterpret_cast<unsigned short*>(&h);
}

__device__ __forceinline__ size_t xzmap(size_t i) {
    return ((i >> 11) << 12) + (i & 2047);
}

// ---------------- LayerNorm -> bf16 out ----------------
__global__ __launch_bounds__(256) void ln_kernel(const float* __restrict__ x,
                                                 const float* __restrict__ w,
                                                 const float* __restrict__ bnorm,
                                                 unsigned short* __restrict__ outb) {
    int row = blockIdx.x;
    const float4* xr = (const float4*)(x + (size_t)row * D_MODEL);
    float4 v = xr[threadIdx.x];
    float s = v.x + v.y + v.z + v.w;
    float sq = v.x * v.x + v.y * v.y + v.z * v.z + v.w * v.w;
#pragma unroll
    for (int off = 32; off > 0; off >>= 1) {
        s += __shfl_down(s, off);
        sq += __shfl_down(sq, off);
    }
    __shared__ float ws[4], wq[4];
    __shared__ float smu, srstd;
    int wave = threadIdx.x >> 6;
    if ((threadIdx.x & 63) == 0) { ws[wave] = s; wq[wave] = sq; }
    __syncthreads();
    if (threadIdx.x == 0) {
        float ts = ws[0] + ws[1] + ws[2] + ws[3];
        float tq = wq[0] + wq[1] + wq[2] + wq[3];
        float mu = ts * (1.f / D_MODEL);
        float var = tq * (1.f / D_MODEL) - mu * mu;
        smu = mu;
        srstd = rsqrtf(var + 1e-5f);
    }
    __syncthreads();
    float mu = smu, rstd = srstd;
    float4 wv = ((const float4*)w)[threadIdx.x];
    float4 bv = ((const float4*)bnorm)[threadIdx.x];
    ushort4 pk;
    pk.x = f2bf((v.x - mu) * rstd * wv.x + bv.x);
    pk.y = f2bf((v.y - mu) * rstd * wv.y + bv.y);
    pk.z = f2bf((v.z - mu) * rstd * wv.z + bv.z);
    pk.w = f2bf((v.w - mu) * rstd * wv.w + bv.w);
    *(ushort4*)(outb + (size_t)row * D_MODEL + threadIdx.x * 4) = pk;
}

// ---------------- weight cast + transpose: W[K][Nreal] f32 -> Wt[Npad][K] bf16 ----------------
__global__ __launch_bounds__(256) void wcast_t(const float* __restrict__ W,
                                               unsigned short* __restrict__ Wt,
                                               int K, int Nreal, int Npad) {
    __shared__ float t[32][33];
    int tn = blockIdx.x * 32, tk = blockIdx.y * 32;
    for (int e = threadIdx.x; e < 1024; e += 256) {
        int r = e >> 5, c = e & 31;
        int n = tn + c;
        t[r][c] = (n < Nreal) ? W[(size_t)(tk + r) * Nreal + n] : 0.f;
    }
    __syncthreads();
    for (int e = threadIdx.x; e < 1024; e += 256) {
        int r = e >> 5, c = e & 31;
        Wt[(size_t)(tn + r) * K + tk + c] = f2bf(t[c][r]);
    }
}

// ---------------- bf16 MFMA GEMM: C = A[M][K] @ Bt[N][K]^T ----------------
// 128x128 tile, BK=32, 4 waves, global_load_lds, bijective XCD swizzle (m204).
// grid (N/128, M/128, KS). KS>1 -> partials at C + z*M*ldc. EPI: 0 none, 2 softplus(x+bias[col])
template <int EPI>
__global__ __launch_bounds__(256) void gemm_bf16(const unsigned short* __restrict__ A,
                                                 const unsigned short* __restrict__ Bt,
                                                 const float* __restrict__ bias,
                                                 float* __restrict__ C,
                                                 int M, int K, int ldc, int Nreal) {
    __shared__ unsigned short As[128 * 32];
    __shared__ unsigned short Bs[128 * 32];
    // XCD-aware bijective swizzle on the x-y plane
    int nwg = gridDim.x * gridDim.y;
    int orig = blockIdx.y * gridDim.x + blockIdx.x;
    int q = nwg >> 3, r = nwg & 7;
    int xcd = orig & 7, idx = orig >> 3;
    int newid = (xcd < r ? xcd * (q + 1) : r * (q + 1) + (xcd - r) * q) + idx;
    int bx = newid % gridDim.x, by = newid / gridDim.x;

    int tid = threadIdx.x;
    int lane = tid & 63;
    int wave = tid >> 6;
    int wr = (wave >> 1) * 64, wc = (wave & 1) * 64;
    int bm = by * 128, bn = bx * 128;
    int kchunk = K / gridDim.z;
    int kbeg = blockIdx.z * kchunk;

    f32x4 acc[4][4];
#pragma unroll
    for (int i = 0; i < 4; ++i)
#pragma unroll
        for (int j = 0; j < 4; ++j) acc[i][j] = (f32x4){0.f, 0.f, 0.f, 0.f};

    int r0 = tid >> 2;
    int c0 = (tid & 3) * 8;
    const unsigned short* a0 = A + (size_t)(bm + r0) * K + c0;
    const unsigned short* a1 = A + (size_t)(bm + 64 + r0) * K + c0;
    const unsigned short* b0 = Bt + (size_t)(bn + r0) * K + c0;
    const unsigned short* b1 = Bt + (size_t)(bn + 64 + r0) * K + c0;
    unsigned short* asw0 = As + (size_t)(tid & ~63) * 8;
    unsigned short* asw1 = As + 2048 + (size_t)(tid & ~63) * 8;
    unsigned short* bsw0 = Bs + (size_t)(tid & ~63) * 8;
    unsigned short* bsw1 = Bs + 2048 + (size_t)(tid & ~63) * 8;

    int ar = lane & 15;
    int ko = (lane >> 4) * 8;

    for (int k0 = kbeg; k0 < kbeg + kchunk; k0 += 32) {
        __syncthreads();
        __builtin_amdgcn_global_load_lds((const __attribute__((address_space(1))) void*)(a0 + k0),
                                         (__attribute__((address_space(3))) void*)asw0, 16, 0, 0);
        __builtin_amdgcn_global_load_lds((const __attribute__((address_space(1))) void*)(a1 + k0),
                                         (__attribute__((address_space(3))) void*)asw1, 16, 0, 0);
        __builtin_amdgcn_global_load_lds((const __attribute__((address_space(1))) void*)(b0 + k0),
                                         (__attribute__((address_space(3))) void*)bsw0, 16, 0, 0);
        __builtin_amdgcn_global_load_lds((const __attribute__((address_space(1))) void*)(b1 + k0),
                                         (__attribute__((address_space(3))) void*)bsw1, 16, 0, 0);
        __syncthreads();
        bf16x8 af[4], bfr[4];
#pragma unroll
        for (int i = 0; i < 4; ++i)
            af[i] = *(const bf16x8*)&As[(size_t)(wr + i * 16 + ar) * 32 + ko];
#pragma unroll
        for (int j = 0; j < 4; ++j)
            bfr[j] = *(const bf16x8*)&Bs[(size_t)(wc + j * 16 + ar) * 32 + ko];
#pragma unroll
        for (int i = 0; i < 4; ++i)
#pragma unroll
            for (int j = 0; j < 4; ++j)
                acc[i][j] = __builtin_amdgcn_mfma_f32_16x16x32_bf16(af[i], bfr[j], acc[i][j], 0, 0, 0);
    }

    int crow0 = bm + wr + (lane >> 4) * 4;
    int ccol0 = bn + wc + (lane & 15);
    size_t zoff = (size_t)blockIdx.z * (size_t)M * ldc;
#pragma unroll
    for (int i = 0; i < 4; ++i)
#pragma unroll
        for (int j = 0; j < 4; ++j) {
            int col = ccol0 + j * 16;
            if (col < Nreal) {
                float* cp = C + zoff + (size_t)(crow0 + i * 16) * ldc + col;
#pragma unroll
                for (int rr = 0; rr < 4; ++rr) {
                    float v = acc[i][j][rr];
                    if (EPI == 2) {
                        v += bias[col];
                        v = (v > 20.f) ? v : log1pf(__expf(v));
                    }
                    cp[(size_t)rr * ldc] = v;
                }
            }
        }
}

// ---------------- split-K reduce for xp (KS=16) + bf16 dt_r extract ----------------
__global__ __launch_bounds__(256) void reduce_xp(const float* __restrict__ part,
                                                 float* __restrict__ xp,
                                                 unsigned short* __restrict__ dtr) {
    int t = blockIdx.x * 256 + threadIdx.x;
    float s = 0.f;
#pragma unroll
    for (int k = 0; k < 16; ++k) s += part[(size_t)k * (NROWS * XPN) + t];
    xp[t] = s;
    int row = t / 96, col = t - row * 96;
    if (col < 64) dtr[(size_t)row * 64 + col] = f2bf(s);
}

// ---------------- split-K reduce for out (KS=4), float4 ----------------
__global__ __launch_bounds__(256) void reduce_out(const float* __restrict__ part,
                                                  float* __restrict__ out) {
    int t = blockIdx.x * 256 + threadIdx.x;
    const float4* p = (const float4*)part;
    float4 a = p[t];
    float4 b = p[t + 524288];
    float4 c = p[t + 2 * 524288];
    float4 d = p[t + 3 * 524288];
    float4 o;
    o.x = a.x + b.x + c.x + d.x;
    o.y = a.y + b.y + c.y + d.y;
    o.z = a.z + b.z + c.z + d.z;
    o.w = a.w + b.w + c.w + d.w;
    ((float4*)out)[t] = o;
}

// ---------------- causal depthwise conv (k=4) + SiLU, 4 channels/thread ----------------
__global__ __launch_bounds__(256) void conv_silu_kernel(const float* __restrict__ xz,
                                                        const float* __restrict__ cw,
                                                        const float* __restrict__ cb,
                                                        float* __restrict__ out,
                                                        unsigned short* __restrict__ outb) {
    int gid = blockIdx.x * 256 + threadIdx.x;
    int d4 = (gid & 511) << 2;
    int bl = gid >> 9;
    int l = bl & (LSEQ - 1);
    const float* base = xz + (size_t)bl * (2 * D_INNER) + d4;
    float4 zr = make_float4(0.f, 0.f, 0.f, 0.f);
    float4 x0 = *(const float4*)base;
    float4 x1 = (l >= 1) ? *(const float4*)(base - 2 * D_INNER) : zr;
    float4 x2 = (l >= 2) ? *(const float4*)(base - 4 * D_INNER) : zr;
    float4 x3 = (l >= 3) ? *(const float4*)(base - 6 * D_INNER) : zr;
    float4 bias = *(const float4*)(cb + d4);
    float res[4];
    const float4* wv = (const float4*)(cw + (size_t)d4 * 4);
    float xs0[4] = {x0.x, x0.y, x0.z, x0.w};
    float xs1[4] = {x1.x, x1.y, x1.z, x1.w};
    float xs2[4] = {x2.x, x2.y, x2.z, x2.w};
    float xs3[4] = {x3.x, x3.y, x3.z, x3.w};
    float bs[4] = {bias.x, bias.y, bias.z, bias.w};
#pragma unroll
    for (int e = 0; e < 4; ++e) {
        float4 we = wv[e];
        float acc = bs[e];
        acc = fmaf(we.w, xs0[e], acc);
        acc = fmaf(we.z, xs1[e], acc);
        acc = fmaf(we.y, xs2[e], acc);
        acc = fmaf(we.x, xs3[e], acc);
        res[e] = acc / (1.f + __expf(-acc));
    }
    size_t oidx = (size_t)bl * D_INNER + d4;
    *(float4*)(out + oidx) = make_float4(res[0], res[1], res[2], res[3]);
    ushort4 ob;
    ob.x = f2bf(res[0]); ob.y = f2bf(res[1]); ob.z = f2bf(res[2]); ob.w = f2bf(res[3]);
    *(ushort4*)(outb + oidx) = ob;
}

// ---------------- scan phase 1: per-chunk local scan (h0 = 0) ----------------
__global__ __launch_bounds__(256) void scan_local(const float* __restrict__ xp,
                                                  const float* __restrict__ delta,
                                                  const float* __restrict__ xc,
                                                  const float* __restrict__ A_log,
                                                  float* __restrict__ xzh,
                                                  float* __restrict__ sdel) {
    int bc = blockIdx.x >> 3;
    int b = bc >> 5, c = bc & (NC - 1);
    int d = (blockIdx.x & 7) * 256 + threadIdx.x;
    int base_r = b * LSEQ + c * CL;
    __shared__ float Bs[CL * 16];
    for (int e = threadIdx.x; e < CL * 16; e += 256) {
        int l = e >> 4, n = e & 15;
        Bs[e] = xp[(size_t)(base_r + l) * XPN + DT_RANK + n];
    }
    __syncthreads();
    float Av[16];
    const float4* ap = (const float4*)(A_log + (size_t)d * 16);
#pragma unroll
    for (int qq = 0; qq < 4; ++qq) {
        float4 a = ap[qq];
        Av[4 * qq + 0] = -__expf(a.x); Av[4 * qq + 1] = -__expf(a.y);
        Av[4 * qq + 2] = -__expf(a.z); Av[4 * qq + 3] = -__expf(a.w);
    }
    float h[16] = {};
    float sd = 0.f;
    const float* dp = delta + (size_t)base_r * D_INNER + d;
    const float* up = xc + (size_t)base_r * D_INNER + d;
#pragma unroll 4
    for (int l = 0; l < CL; ++l) {
        float dv = dp[(size_t)l * D_INNER];
        float u = up[(size_t)l * D_INNER];
        float du = dv * u;
        sd += dv;
#pragma unroll
        for (int n = 0; n < 16; ++n) {
            float dA = __expf(dv * Av[n]);
            h[n] = fmaf(dA, h[n], du * Bs[l * 16 + n]);
        }
    }
    size_t hi = ((size_t)(c * NB + b) * D_INNER + d) * 16;
#pragma unroll
    for (int qq = 0; qq < 4; ++qq) {
        float4 v = make_float4(h[4 * qq], h[4 * qq + 1], h[4 * qq + 2], h[4 * qq + 3]);
        *(float4*)(xzh + xzmap(hi + 4 * qq)) = v;
    }
    sdel[(size_t)(c * NB + b) * D_INNER + d] = sd;
}

// ---------------- scan phase 2: cross-chunk combine ----------------
__global__ __launch_bounds__(256) void scan_combine(const float* __restrict__ A_log,
                                                    const float* __restrict__ sdel,
                                                    float* __restrict__ xzh) {
    int t = blockIdx.x * 256 + threadIdx.x;
    int n = t & 15, d = (t >> 4) & (D_INNER - 1), b = t >> 15;
    float Avn = -__expf(A_log[(size_t)d * 16 + n]);
    float h = 0.f;
#pragma unroll 4
    for (int c = 0; c < NC; ++c) {
        size_t base = (size_t)(c * NB + b) * D_INNER + d;
        float S = sdel[base];
        float* hp = xzh + xzmap(base * 16 + n);
        float tmp = *hp;
        *hp = h;
        h = fmaf(__expf(Avn * S), h, tmp);
    }
}

// ---------------- scan phase 3: finalize, fuse silu(z) gate -> bf16 y ----------------
__global__ __launch_bounds__(256) void scan_final(const float* __restrict__ xp,
                                                  const float* __restrict__ dlt,
                                                  const float* __restrict__ xc,
                                                  const float* __restrict__ xz,
                                                  const float* __restrict__ A_log,
                                                  const float* __restrict__ Dp,
                                                  unsigned short* __restrict__ yb) {
    int bc = blockIdx.x >> 3;
    int b = bc >> 5, c = bc & (NC - 1);
    int d = (blockIdx.x & 7) * 256 + threadIdx.x;
    int base_r = b * LSEQ + c * CL;
    __shared__ float Bs[CL * 16], Cs[CL * 16];
    for (int e = threadIdx.x; e < CL * 16; e += 256) {
        int l = e >> 4, n = e & 15;
        Bs[e] = xp[(size_t)(base_r + l) * XPN + DT_RANK + n];
        Cs[e] = xp[(size_t)(base_r + l) * XPN + DT_RANK + 16 + n];
    }
    __syncthreads();
    float Av[16];
    const float4* ap = (const float4*)(A_log + (size_t)d * 16);
#pragma unroll
    for (int qq = 0; qq < 4; ++qq) {
        float4 a = ap[qq];
        Av[4 * qq + 0] = -__expf(a.x); Av[4 * qq + 1] = -__expf(a.y);
        Av[4 * qq + 2] = -__expf(a.z); Av[4 * qq + 3] = -__expf(a.w);
    }
    float h[16];
    size_t hi = ((size_t)(c * NB + b) * D_INNER + d) * 16;
#pragma unroll
    for (int qq = 0; qq < 4; ++qq) {
        float4 v = *(const float4*)(xz + xzmap(hi + 4 * qq));
        h[4 * qq] = v.x; h[4 * qq + 1] = v.y; h[4 * qq + 2] = v.z; h[4 * qq + 3] = v.w;
    }
    float Dv = Dp[d];
    const float* dyp = dlt + (size_t)base_r * D_INNER + d;
    const float* up = xc + (size_t)base_r * D_INNER + d;
    const float* zp = xz + (size_t)base_r * (2 * D_INNER) + D_INNER + d;
#pragma unroll 4
    for (int l = 0; l < CL; ++l) {
        float dv = dyp[(size_t)l * D_INNER];
        float u = up[(size_t)l * D_INNER];
        float du = dv * u;
        float acc = 0.f;
#pragma unroll
        for (int n = 0; n < 16; ++n) {
            float dA = __expf(dv * Av[n]);
            h[n] = fmaf(dA, h[n], du * Bs[l * 16 + n]);
            acc = fmaf(h[n], Cs[l * 16 + n], acc);
        }
        float yv = fmaf(u, Dv, acc);
        float zv = zp[(size_t)l * (2 * D_INNER)];
        float sz = zv / (1.f + __expf(-zv));
        yb[(size_t)(base_r + l) * D_INNER + d] = f2bf(yv * sz);
    }
}

extern "C" void kernel_launch(void* const* d_in, const int* in_sizes, int n_in,
                              void* d_out, int out_size, void* d_ws, size_t ws_size,
                              hipStream_t stream) {
    const float* hidden = (const float*)d_in[0];
    const float* norm_w = (const float*)d_in[1];
    const float* norm_b = (const float*)d_in[2];
    const float* in_proj_w = (const float*)d_in[3];
    const float* conv_w = (const float*)d_in[4];
    const float* conv_b = (const float*)d_in[5];
    const float* x_proj_w = (const float*)d_in[6];
    const float* dt_proj_w = (const float*)d_in[7];
    const float* dt_proj_b = (const float*)d_in[8];
    const float* A_log = (const float*)d_in[9];
    const float* D_param = (const float*)d_in[10];
    const float* out_proj_w = (const float*)d_in[11];
    float* out = (float*)d_out;

    float* wsf = (float*)d_ws;
    // region 0: [0 .. 1,048,576) floats — time-shared
    unsigned short* hbufb = (unsigned short*)wsf;             // LN out bf16 [2048][1024] (dies at in_proj)
    float* xpbuf = wsf;                                       // xp f32 [2048][96]
    float* sdelbuf = wsf + 196608;                            // [64][2048]
    unsigned short* dtrb = (unsigned short*)(wsf + 327680);   // dt_r bf16 [2048][64] (131072 floats)
    unsigned short* wDt = (unsigned short*)(wsf + 458752);    // dt_proj_w^T bf16 [2048][64] (65536 floats)
    unsigned short* wOt = (unsigned short*)wsf;               // out_proj_w^T bf16 (after scan_final)
    float* xzbuf = wsf + 1048576;                             // f32 [2048][4096]; later out partials [4][2048][1024]
    float* xcbuf = xzbuf + 8388608;                           // f32 [2048][2048]
    unsigned short* xcb = (unsigned short*)(xcbuf + 4194304); // conv out bf16 [2048][2048]
    unsigned short* yb = xcb;                                 // y bf16 (after x_proj)
    float* dltbuf = xcbuf + 4194304 + 2097152;                // f32 [2048][2048] — time-shared:
    unsigned short* wAt = (unsigned short*)dltbuf;            //   in_proj_w^T bf16 [4096][1024]
    float* xpart = dltbuf;                                    //   x_proj partials [16][2048][96] (3,145,728 f)
    unsigned short* wXt = (unsigned short*)(dltbuf + 3145728);//   x_proj_w^T bf16 [128][2048]

    // weight casts
    wcast_t<<<dim3(4096 / 32, 1024 / 32), 256, 0, stream>>>(in_proj_w, wAt, 1024, 4096, 4096);
    wcast_t<<<dim3(128 / 32, 2048 / 32), 256, 0, stream>>>(x_proj_w, wXt, 2048, 96, 128);

    // LayerNorm -> bf16
    ln_kernel<<<NROWS, 256, 0, stream>>>(hidden, norm_w, norm_b, hbufb);

    // xz = h @ in_proj_w
    gemm_bf16<0><<<dim3(4096 / 128, NROWS / 128, 1), 256, 0, stream>>>(
        hbufb, wAt, nullptr, xzbuf, NROWS, 1024, 4096, 4096);

    // dt weight cast (region 0 slot free once in_proj consumed hbufb)
    wcast_t<<<dim3(2048 / 32, 64 / 32), 256, 0, stream>>>(dt_proj_w, wDt, 64, 2048, 2048);

    // conv + silu -> f32 + bf16
    conv_silu_kernel<<<(NROWS * D_INNER) / 1024, 256, 0, stream>>>(xzbuf, conv_w, conv_b, xcbuf, xcb);

    // xp partials = xc @ x_proj_w (split-K = 16)
    gemm_bf16<0><<<dim3(1, NROWS / 128, 16), 256, 0, stream>>>(
        xcb, wXt, nullptr, xpart, NROWS, 2048, XPN, XPN);

    // reduce partials -> xp f32 + dt_r bf16
    reduce_xp<<<(NROWS * XPN) / 256, 256, 0, stream>>>(xpart, xpbuf, dtrb);

    // delta = softplus(dt_r @ dt_proj_w + b)  (MFMA bf16, fused epilogue)
    gemm_bf16<2><<<dim3(D_INNER / 128, NROWS / 128, 1), 256, 0, stream>>>(
        dtrb, wDt, dt_proj_b, dltbuf, NROWS, 64, D_INNER, D_INNER);

    // chunked selective scan + fused gate -> bf16 y
    scan_local<<<NB * NC * (D_INNER / 256), 256, 0, stream>>>(
        xpbuf, dltbuf, xcbuf, A_log, xzbuf, sdelbuf);
    scan_combine<<<(NB * D_INNER * D_STATE) / 256, 256, 0, stream>>>(
        A_log, sdelbuf, xzbuf);
    scan_final<<<NB * NC * (D_INNER / 256), 256, 0, stream>>>(
        xpbuf, dltbuf, xcbuf, xzbuf, A_log, D_param, yb);

    // out_proj weight cast (region 0 fully dead after scan_final)
    wcast_t<<<dim3(1024 / 32, 2048 / 32), 256, 0, stream>>>(out_proj_w, wOt, 2048, 1024, 1024);

    // out partials = y @ out_proj_w (split-K = 4; partials in dead xzbuf)
    gemm_bf16<0><<<dim3(1024 / 128, NROWS / 128, 4), 256, 0, stream>>>(
        yb, wOt, nullptr, xzbuf, NROWS, 2048, 1024, 1024);

    // reduce out partials -> d_out
    reduce_out<<<(NROWS * D_MODEL / 4) / 256, 256, 0, stream>>>(xzbuf, out);
}